// Round 1
// baseline (226.759 us; speedup 1.0000x reference)
//
#include <hip/hip_runtime.h>

typedef unsigned short u16;
typedef float f32x4 __attribute__((ext_vector_type(4)));
typedef __bf16 bf16x8 __attribute__((ext_vector_type(8)));
typedef u16 u16x4 __attribute__((ext_vector_type(4)));

#define MFMA_16x16x32(a, b, c) __builtin_amdgcn_mfma_f32_16x16x32_bf16((a), (b), (c), 0, 0, 0)

// ---------- helpers ----------

__device__ __forceinline__ u16 f2bf(float f) {
  unsigned u = __builtin_bit_cast(unsigned, f);
  unsigned r = ((u >> 16) & 1u) + 0x7FFFu;  // round-to-nearest-even
  return (u16)((u + r) >> 16);
}

// async global->LDS, 16B per lane. LDS dest must be wave-uniform base + lane*16.
__device__ __forceinline__ void gload16(const void* g, void* l) {
  __builtin_amdgcn_global_load_lds(
      (const __attribute__((address_space(1))) void*)g,
      (__attribute__((address_space(3))) void*)l, 16, 0, 0);
}

// ---------- conversion kernels ----------

__global__ void cvt_to_bf16(const float* __restrict__ in, u16* __restrict__ out, int n) {
  const int i = (blockIdx.x * 256 + threadIdx.x) * 8;
  if (i >= n) return;
  const f32x4 a = *(const f32x4*)(in + i);
  const f32x4 b = *(const f32x4*)(in + i + 4);
  u16x4 u0, u1;
#pragma unroll
  for (int j = 0; j < 4; ++j) { u0[j] = f2bf(a[j]); u1[j] = f2bf(b[j]); }
  *(u16x4*)(out + i) = u0;
  *(u16x4*)(out + i + 4) = u1;
}

// in [rows][cols] fp32  ->  out [cols][rows] bf16   (64x64 LDS tiles)
__global__ void transpose_cvt(const float* __restrict__ in, u16* __restrict__ out,
                              int rows, int cols) {
  __shared__ float t[64][65];
  const int rb = blockIdx.y * 64, cb = blockIdx.x * 64;
  for (int i = threadIdx.x; i < 4096; i += 256) {
    const int r = i >> 6, c = i & 63;
    t[r][c] = in[(size_t)(rb + r) * cols + cb + c];
  }
  __syncthreads();
  for (int i = threadIdx.x; i < 4096; i += 256) {
    const int r = i >> 6, c = i & 63;
    out[(size_t)(cb + r) * rows + rb + c] = f2bf(t[c][r]);
  }
}

// ---------- GEMM: C[M][N] = A[M][K] * Bt[N][K]^T + bias ----------
// 128x128 tile, BK=32, 4 waves each owning a 64x64 sub-tile (4x4 of 16x16 frags).
// EPI=0: scatter to q[bh][t][64], k[bh][t][64], vT[bh][64][t] (bf16, +bias)
// EPI=1: fp32 out[M][N] + bias
template <int EPI>
__global__ __launch_bounds__(256, 2) void gemm_bt(
    const u16* __restrict__ A, const u16* __restrict__ Bt, int K,
    const float* __restrict__ bias,
    u16* __restrict__ oq, u16* __restrict__ ok, u16* __restrict__ ov,
    float* __restrict__ of, int N, int nbx) {
  __shared__ __align__(16) u16 As[128 * 32];
  __shared__ __align__(16) u16 Bs[128 * 32];
  const int tid = threadIdx.x;
  const int lane = tid & 63, w = tid >> 6;
  const int g = lane >> 4, cc = lane & 15;
  const int wr = w >> 1, wc = w & 1;
  const int bid = blockIdx.x;
  const int bx = bid % nbx, by = bid / nbx;

  // staging: chunk ch in [0,512): row=ch>>2, kchunk=(ch&3)*8; thread owns ch=tid and tid+256
  const u16* pa = A + (size_t)(by * 128 + (tid >> 2)) * K + (tid & 3) * 8;
  const u16* pb = Bt + (size_t)(bx * 128 + (tid >> 2)) * K + (tid & 3) * 8;
  u16* la = &As[tid * 8];
  u16* lb = &Bs[tid * 8];
  const size_t rowskip = (size_t)64 * K;

  f32x4 acc[4][4] = {};
  const int aoff = (wr * 64 + cc) * 32 + g * 8;
  const int boff = (wc * 64 + cc) * 32 + g * 8;

  for (int k0 = 0; k0 < K; k0 += 32) {
    gload16(pa + k0, la);
    gload16(pa + rowskip + k0, la + 2048);
    gload16(pb + k0, lb);
    gload16(pb + rowskip + k0, lb + 2048);
    __syncthreads();
    bf16x8 af[4], bf[4];
#pragma unroll
    for (int mi = 0; mi < 4; ++mi) af[mi] = *(const bf16x8*)&As[aoff + mi * 512];
#pragma unroll
    for (int ni = 0; ni < 4; ++ni) bf[ni] = *(const bf16x8*)&Bs[boff + ni * 512];
#pragma unroll
    for (int mi = 0; mi < 4; ++mi)
#pragma unroll
      for (int ni = 0; ni < 4; ++ni)
        acc[mi][ni] = MFMA_16x16x32(af[mi], bf[ni], acc[mi][ni]);
    __syncthreads();
  }

  // epilogue: D layout col=lane&15, row=(lane>>4)*4+r
  const int m00 = by * 128 + wr * 64 + 4 * g;
  const int n00 = bx * 128 + wc * 64;
#pragma unroll
  for (int ni = 0; ni < 4; ++ni) {
    const int n = n00 + ni * 16 + cc;
    const float bn = bias[n];
    if constexpr (EPI == 0) {
      const int which = n >> 10;          // 0=q 1=k 2=v (wave-uniform)
      const int d = n & 1023;
      const int h = d >> 6, dh = d & 63;
#pragma unroll
      for (int mi = 0; mi < 4; ++mi) {
        const int mb = m00 + mi * 16;     // + r, never crosses a 2048 boundary
        const int b = mb >> 11, t = mb & 2047;
        if (which == 2) {
          u16x4 pk;
#pragma unroll
          for (int r = 0; r < 4; ++r) pk[r] = f2bf(acc[mi][ni][r] + bn);
          *(u16x4*)&ov[((size_t)((b * 16 + h) * 64 + dh)) * 2048 + t] = pk;
        } else {
          u16* dst = (which == 0 ? oq : ok) + ((size_t)((b * 16 + h) * 2048 + t)) * 64 + dh;
#pragma unroll
          for (int r = 0; r < 4; ++r) dst[(size_t)r * 64] = f2bf(acc[mi][ni][r] + bn);
        }
      }
    } else {
#pragma unroll
      for (int mi = 0; mi < 4; ++mi) {
        const int m = m00 + mi * 16;
#pragma unroll
        for (int r = 0; r < 4; ++r) of[(size_t)(m + r) * N + n] = acc[mi][ni][r] + bn;
      }
    }
  }
}

// ---------- causal flash attention ----------
// Q,K: [bh][2048][64] bf16. Vt: [bh][64][2048] bf16. Out: [b][t][h*64+dh] bf16.
// Block: 256 thr (4 waves), one (bh, 128-row q-tile). Wave w owns q rows w*32..+31.
// KV tile = 128 rows. K LDS [128][64] chunk-XOR-swizzled via pre-swizzled global src;
// V LDS [64][128] (dh-major) likewise. P via per-wave LDS roundtrip [32][136].
__global__ __launch_bounds__(256, 2) void flash_attn(
    const u16* __restrict__ Qb, const u16* __restrict__ Kb,
    const u16* __restrict__ Vt, u16* __restrict__ Ob) {
  __shared__ __align__(16) u16 Ks[128 * 64];
  __shared__ __align__(16) u16 Vs[64 * 128];
  __shared__ __align__(16) u16 Ps[4][32 * 136];

  const int bid = blockIdx.x;
  const int qt = 15 - (bid >> 6);   // longest tiles first
  const int bh = bid & 63;
  const int tid = threadIdx.x;
  const int lane = tid & 63, w = tid >> 6;
  const int g = lane >> 4, cc = lane & 15;
  const int q0 = qt * 128 + w * 32;

  // Q fragments in registers (A-operand: row=lane&15, k=d contiguous 8)
  bf16x8 aq[2][2];
  {
    const u16* qp = Qb + ((size_t)bh * 2048 + q0 + cc) * 64 + g * 8;
#pragma unroll
    for (int mi = 0; mi < 2; ++mi)
#pragma unroll
      for (int dc = 0; dc < 2; ++dc)
        aq[mi][dc] = *(const bf16x8*)(qp + (size_t)mi * 16 * 64 + dc * 32);
  }

  f32x4 acc_o[2][4] = {};
  float m_run[2][4], l_run[2][4];
#pragma unroll
  for (int mi = 0; mi < 2; ++mi)
#pragma unroll
    for (int r = 0; r < 4; ++r) { m_run[mi][r] = -1e30f; l_run[mi][r] = 0.f; }

  u16* Pw = &Ps[w][0];
  const float sc = 0.18033688011112042f;  // (1/8) * log2(e)

  const int kr0 = tid >> 3, kc0 = tid & 7;    // K staging: chunk = tid+i*256
  const int vdh0 = tid >> 4, vc0 = tid & 15;  // V staging
  const u16* kbase = Kb + (size_t)bh * 2048 * 64;
  const u16* vbase = Vt + (size_t)bh * 64 * 2048;

  for (int kt = 0; kt <= qt; ++kt) {
    __syncthreads();  // previous tile's LDS reads done
#pragma unroll
    for (int i = 0; i < 4; ++i) {
      const int kr = kr0 + i * 32;
      gload16(kbase + ((size_t)(kt * 128 + kr)) * 64 + ((kc0 ^ (kr & 7)) * 8),
              &Ks[(tid + i * 256) * 8]);
    }
#pragma unroll
    for (int i = 0; i < 4; ++i) {
      const int dh = vdh0 + i * 16;
      gload16(vbase + (size_t)dh * 2048 + kt * 128 + ((vc0 ^ (dh & 15)) * 8),
              &Vs[(tid + i * 256) * 8]);
    }
    __syncthreads();  // drains vmcnt

    // S = Q K^T : s[mi][ki], D row = q off (4g+r), col = k off (cc)
    f32x4 s[2][8] = {};
#pragma unroll
    for (int dc = 0; dc < 2; ++dc)
#pragma unroll
      for (int ki = 0; ki < 8; ++ki) {
        const int kr = ki * 16 + cc;
        const bf16x8 bk = *(const bf16x8*)&Ks[kr * 64 + (((4 * dc + g) ^ (kr & 7))) * 8];
#pragma unroll
        for (int mi = 0; mi < 2; ++mi) s[mi][ki] = MFMA_16x16x32(aq[mi][dc], bk, s[mi][ki]);
      }

    if (kt == qt) {  // causal mask on diagonal tile
#pragma unroll
      for (int mi = 0; mi < 2; ++mi)
#pragma unroll
        for (int ki = 0; ki < 8; ++ki) {
          const int koff = ki * 16 + cc;
          const int qoff = w * 32 + mi * 16 + 4 * g;
#pragma unroll
          for (int r = 0; r < 4; ++r)
            if (koff > qoff + r) s[mi][ki][r] = -1e30f;
        }
    }

    // row max (raw units) -> running max (log2-scaled units), rescale factors
    float sf_[2][4];
#pragma unroll
    for (int mi = 0; mi < 2; ++mi)
#pragma unroll
      for (int r = 0; r < 4; ++r) {
        float mx = s[mi][0][r];
#pragma unroll
        for (int ki = 1; ki < 8; ++ki) mx = fmaxf(mx, s[mi][ki][r]);
        mx = fmaxf(mx, __shfl_xor(mx, 1));
        mx = fmaxf(mx, __shfl_xor(mx, 2));
        mx = fmaxf(mx, __shfl_xor(mx, 4));
        mx = fmaxf(mx, __shfl_xor(mx, 8));
        const float mn = fmaxf(m_run[mi][r], mx * sc);
        const float sf = exp2f(m_run[mi][r] - mn);
        m_run[mi][r] = mn;
        l_run[mi][r] *= sf;
        sf_[mi][r] = sf;
      }
#pragma unroll
    for (int mi = 0; mi < 2; ++mi)
#pragma unroll
      for (int ni = 0; ni < 4; ++ni)
#pragma unroll
        for (int r = 0; r < 4; ++r) acc_o[mi][ni][r] *= sf_[mi][r];

    // P = exp2(s*sc - m); row-sum; write bf16 P to per-wave LDS
#pragma unroll
    for (int mi = 0; mi < 2; ++mi) {
      float rs[4] = {0.f, 0.f, 0.f, 0.f};
#pragma unroll
      for (int ki = 0; ki < 8; ++ki) {
#pragma unroll
        for (int r = 0; r < 4; ++r) {
          const float p = exp2f(s[mi][ki][r] * sc - m_run[mi][r]);
          rs[r] += p;
          Pw[(mi * 16 + 4 * g + r) * 136 + ki * 16 + cc] = f2bf(p);
        }
      }
#pragma unroll
      for (int r = 0; r < 4; ++r) {
        float v = rs[r];
        v += __shfl_xor(v, 1);
        v += __shfl_xor(v, 2);
        v += __shfl_xor(v, 4);
        v += __shfl_xor(v, 8);
        l_run[mi][r] += v;
      }
    }

    asm volatile("s_waitcnt lgkmcnt(0)" ::: "memory");  // P writes -> P reads (same wave)

    // O += P V
#pragma unroll
    for (int kc = 0; kc < 4; ++kc) {
      bf16x8 ap[2], bv[4];
#pragma unroll
      for (int mi = 0; mi < 2; ++mi)
        ap[mi] = *(const bf16x8*)&Pw[(mi * 16 + cc) * 136 + kc * 32 + g * 8];
#pragma unroll
      for (int ni = 0; ni < 4; ++ni) {
        const int dh = ni * 16 + cc;
        bv[ni] = *(const bf16x8*)&Vs[dh * 128 + (((4 * kc + g) ^ (dh & 15))) * 8];
      }
#pragma unroll
      for (int mi = 0; mi < 2; ++mi)
#pragma unroll
        for (int ni = 0; ni < 4; ++ni)
          acc_o[mi][ni] = MFMA_16x16x32(ap[mi], bv[ni], acc_o[mi][ni]);
    }
  }

  // epilogue: O/l -> [b][t][h*64+dh] bf16
  const int b = bh >> 4, h = bh & 15;
#pragma unroll
  for (int mi = 0; mi < 2; ++mi) {
    float inv[4];
#pragma unroll
    for (int r = 0; r < 4; ++r) inv[r] = 1.f / l_run[mi][r];
#pragma unroll
    for (int ni = 0; ni < 4; ++ni)
#pragma unroll
      for (int r = 0; r < 4; ++r) {
        const int tq = q0 + mi * 16 + 4 * g + r;
        Ob[((size_t)(b * 2048 + tq)) * 1024 + h * 64 + ni * 16 + cc] =
            f2bf(acc_o[mi][ni][r] * inv[r]);
      }
  }
}

// ---------- launch ----------

extern "C" void kernel_launch(void* const* d_in, const int* in_sizes, int n_in,
                              void* d_out, int out_size, void* d_ws, size_t ws_size,
                              hipStream_t stream) {
  const float* x     = (const float*)d_in[0];
  const float* w_qkv = (const float*)d_in[1];
  const float* b_qkv = (const float*)d_in[2];
  const float* w_out = (const float*)d_in[3];
  const float* b_out = (const float*)d_in[4];
  float* out = (float*)d_out;
  char* ws = (char*)d_ws;

  // workspace layout (bytes); xb region is reused as the attention output
  u16* xb    = (u16*)(ws + 0);          // 8192*1024 bf16 = 16 MB (then attn out)
  u16* wqkvT = (u16*)(ws + 16777216);   // 3072*1024 bf16 = 6 MB
  u16* woutT = (u16*)(ws + 23068672);   // 1024*1024 bf16 = 2 MB
  u16* qbuf  = (u16*)(ws + 25165824);   // 64*2048*64 bf16 = 16 MB
  u16* kbuf  = (u16*)(ws + 41943040);   // 16 MB
  u16* vbuf  = (u16*)(ws + 58720256);   // 16 MB (transposed: [bh][64][2048])
  // total 72 MB

  cvt_to_bf16<<<4096, 256, 0, stream>>>(x, xb, 8388608);
  transpose_cvt<<<dim3(48, 16), 256, 0, stream>>>(w_qkv, wqkvT, 1024, 3072);
  transpose_cvt<<<dim3(16, 16), 256, 0, stream>>>(w_out, woutT, 1024, 1024);
  // QKV projection: M=8192 N=3072 K=1024
  gemm_bt<0><<<24 * 64, 256, 0, stream>>>(xb, wqkvT, 1024, b_qkv,
                                          qbuf, kbuf, vbuf, nullptr, 3072, 24);
  // attention (writes [b][t][1024] bf16 into xb region)
  flash_attn<<<1024, 256, 0, stream>>>(qbuf, kbuf, vbuf, xb);
  // output projection: M=8192 N=1024 K=1024 -> fp32 d_out
  gemm_bt<1><<<8 * 64, 256, 0, stream>>>(xb, woutT, 1024, b_out,
                                         nullptr, nullptr, nullptr, out, 1024, 8);
}

// Round 2
// 207.338 us; speedup vs baseline: 1.0937x; 1.0937x over previous
//
#include <hip/hip_runtime.h>

typedef unsigned short u16;
typedef float f32x4 __attribute__((ext_vector_type(4)));
typedef __bf16 bf16x8 __attribute__((ext_vector_type(8)));
typedef __bf16 bf16x4 __attribute__((ext_vector_type(4)));
typedef short s16x4 __attribute__((ext_vector_type(4)));
typedef u16 u16x4 __attribute__((ext_vector_type(4)));

#define MFMA_16x16x32(a, b, c) __builtin_amdgcn_mfma_f32_16x16x32_bf16((a), (b), (c), 0, 0, 0)

__device__ __forceinline__ f32x4 MFMA16(bf16x4 a, bf16x4 b, f32x4 c) {
#if __has_builtin(__builtin_amdgcn_mfma_f32_16x16x16_bf16)
  return __builtin_amdgcn_mfma_f32_16x16x16_bf16(a, b, c, 0, 0, 0);
#elif __has_builtin(__builtin_amdgcn_mfma_f32_16x16x16bf16_1k)
  return __builtin_amdgcn_mfma_f32_16x16x16bf16_1k(
      __builtin_bit_cast(s16x4, a), __builtin_bit_cast(s16x4, b), c, 0, 0, 0);
#else
  asm("v_mfma_f32_16x16x16_bf16 %0, %1, %2, %0" : "+v"(c) : "v"(a), "v"(b));
  return c;
#endif
}

// ---------- helpers ----------

__device__ __forceinline__ u16 f2bf(float f) {
  unsigned u = __builtin_bit_cast(unsigned, f);
  unsigned r = ((u >> 16) & 1u) + 0x7FFFu;  // round-to-nearest-even
  return (u16)((u + r) >> 16);
}

// async global->LDS, 16B per lane. LDS dest must be wave-uniform base + lane*16.
__device__ __forceinline__ void gload16(const void* g, void* l) {
  __builtin_amdgcn_global_load_lds(
      (const __attribute__((address_space(1))) void*)g,
      (__attribute__((address_space(3))) void*)l, 16, 0, 0);
}

// ---------- conversion kernels ----------

__global__ void cvt_to_bf16(const float* __restrict__ in, u16* __restrict__ out, int n) {
  const int i = (blockIdx.x * 256 + threadIdx.x) * 8;
  if (i >= n) return;
  const f32x4 a = *(const f32x4*)(in + i);
  const f32x4 b = *(const f32x4*)(in + i + 4);
  u16x4 u0, u1;
#pragma unroll
  for (int j = 0; j < 4; ++j) { u0[j] = f2bf(a[j]); u1[j] = f2bf(b[j]); }
  *(u16x4*)(out + i) = u0;
  *(u16x4*)(out + i + 4) = u1;
}

// in [rows][cols] fp32  ->  out [cols][rows] bf16   (64x64 LDS tiles)
__global__ void transpose_cvt(const float* __restrict__ in, u16* __restrict__ out,
                              int rows, int cols) {
  __shared__ float t[64][65];
  const int rb = blockIdx.y * 64, cb = blockIdx.x * 64;
  for (int i = threadIdx.x; i < 4096; i += 256) {
    const int r = i >> 6, c = i & 63;
    t[r][c] = in[(size_t)(rb + r) * cols + cb + c];
  }
  __syncthreads();
  for (int i = threadIdx.x; i < 4096; i += 256) {
    const int r = i >> 6, c = i & 63;
    out[(size_t)(cb + r) * rows + rb + c] = f2bf(t[c][r]);
  }
}

// ---------- GEMM: C[M][N] = A[M][K] * Bt[N][K]^T + bias ----------
template <int EPI>
__global__ __launch_bounds__(256, 2) void gemm_bt(
    const u16* __restrict__ A, const u16* __restrict__ Bt, int K,
    const float* __restrict__ bias,
    u16* __restrict__ oq, u16* __restrict__ ok, u16* __restrict__ ov,
    float* __restrict__ of, int N, int nbx) {
  __shared__ __align__(16) u16 As[128 * 32];
  __shared__ __align__(16) u16 Bs[128 * 32];
  const int tid = threadIdx.x;
  const int lane = tid & 63, w = tid >> 6;
  const int g = lane >> 4, cc = lane & 15;
  const int wr = w >> 1, wc = w & 1;
  const int bid = blockIdx.x;
  const int bx = bid % nbx, by = bid / nbx;

  const u16* pa = A + (size_t)(by * 128 + (tid >> 2)) * K + (tid & 3) * 8;
  const u16* pb = Bt + (size_t)(bx * 128 + (tid >> 2)) * K + (tid & 3) * 8;
  u16* la = &As[tid * 8];
  u16* lb = &Bs[tid * 8];
  const size_t rowskip = (size_t)64 * K;

  f32x4 acc[4][4] = {};
  const int aoff = (wr * 64 + cc) * 32 + g * 8;
  const int boff = (wc * 64 + cc) * 32 + g * 8;

  for (int k0 = 0; k0 < K; k0 += 32) {
    gload16(pa + k0, la);
    gload16(pa + rowskip + k0, la + 2048);
    gload16(pb + k0, lb);
    gload16(pb + rowskip + k0, lb + 2048);
    __syncthreads();
    bf16x8 af[4], bf[4];
#pragma unroll
    for (int mi = 0; mi < 4; ++mi) af[mi] = *(const bf16x8*)&As[aoff + mi * 512];
#pragma unroll
    for (int ni = 0; ni < 4; ++ni) bf[ni] = *(const bf16x8*)&Bs[boff + ni * 512];
#pragma unroll
    for (int mi = 0; mi < 4; ++mi)
#pragma unroll
      for (int ni = 0; ni < 4; ++ni)
        acc[mi][ni] = MFMA_16x16x32(af[mi], bf[ni], acc[mi][ni]);
    __syncthreads();
  }

  const int m00 = by * 128 + wr * 64 + 4 * g;
  const int n00 = bx * 128 + wc * 64;
#pragma unroll
  for (int ni = 0; ni < 4; ++ni) {
    const int n = n00 + ni * 16 + cc;
    const float bn = bias[n];
    if constexpr (EPI == 0) {
      const int which = n >> 10;          // 0=q 1=k 2=v (wave-uniform)
      const int d = n & 1023;
      const int h = d >> 6, dh = d & 63;
#pragma unroll
      for (int mi = 0; mi < 4; ++mi) {
        const int mb = m00 + mi * 16;
        const int b = mb >> 11, t = mb & 2047;
        if (which == 2) {
          u16x4 pk;
#pragma unroll
          for (int r = 0; r < 4; ++r) pk[r] = f2bf(acc[mi][ni][r] + bn);
          *(u16x4*)&ov[((size_t)((b * 16 + h) * 64 + dh)) * 2048 + t] = pk;
        } else {
          u16* dst = (which == 0 ? oq : ok) + ((size_t)((b * 16 + h) * 2048 + t)) * 64 + dh;
#pragma unroll
          for (int r = 0; r < 4; ++r) dst[(size_t)r * 64] = f2bf(acc[mi][ni][r] + bn);
        }
      }
    } else {
#pragma unroll
      for (int mi = 0; mi < 4; ++mi) {
        const int m = m00 + mi * 16;
#pragma unroll
        for (int r = 0; r < 4; ++r) of[(size_t)(m + r) * N + n] = acc[mi][ni][r] + bn;
      }
    }
  }
}

// ---------- causal flash attention (swapped QK^T, register-local PV) ----------
// Q,K: [bh][2048][64] bf16. Vt: [bh][64][2048] bf16. Out: [b][t][h*64+dh] bf16.
// 256 thr / 4 waves; wave owns 32 q rows; KV tile 128.
// S^T = mfma(K, Q): lane (g,cc) holds S[k=16ki+4g+r][q=cc(+16mi)] -> softmax stats
// are 2 scalars/lane; P's lane layout IS the 16x16x16 A-operand layout (k=4g+j),
// so PV consumes P directly from registers. No P LDS buffer.
__global__ __launch_bounds__(256, 4) void flash_attn(
    const u16* __restrict__ Qb, const u16* __restrict__ Kb,
    const u16* __restrict__ Vt, u16* __restrict__ Ob) {
  __shared__ __align__(16) u16 Ks[128 * 64];
  __shared__ __align__(16) u16 Vs[64 * 128];

  const int bid = blockIdx.x;
  const int qt = 15 - (bid >> 6);   // longest tiles first
  const int bh = bid & 63;
  const int tid = threadIdx.x;
  const int lane = tid & 63, w = tid >> 6;
  const int g = lane >> 4, cc = lane & 15;
  const int q0 = qt * 128 + w * 32;

  // Q as B-operand fragments: Q[q0+mi*16+cc][dc*32+g*8 .. +7]
  bf16x8 bq[2][2];
  {
    const u16* qp = Qb + ((size_t)bh * 2048 + q0 + cc) * 64 + g * 8;
#pragma unroll
    for (int mi = 0; mi < 2; ++mi)
#pragma unroll
      for (int dc = 0; dc < 2; ++dc)
        bq[mi][dc] = *(const bf16x8*)(qp + (size_t)mi * 16 * 64 + dc * 32);
  }

  f32x4 acc[2][4] = {};
  float m_run[2] = {-1e30f, -1e30f};
  float l_run[2] = {0.f, 0.f};
  const float sc = 0.18033688011112042f;  // (1/8) * log2(e)

  const int kr0 = tid >> 3, kc0 = tid & 7;
  const int vdh0 = tid >> 4, vc0 = tid & 15;
  const u16* kbase = Kb + (size_t)bh * 2048 * 64;
  const u16* vbase = Vt + (size_t)bh * 64 * 2048;

  for (int kt = 0; kt <= qt; ++kt) {
    __syncthreads();  // previous tile's LDS reads done
#pragma unroll
    for (int i = 0; i < 4; ++i) {
      const int kr = kr0 + i * 32;
      gload16(kbase + ((size_t)(kt * 128 + kr)) * 64 + ((kc0 ^ (kr & 7)) * 8),
              &Ks[(tid + i * 256) * 8]);
    }
#pragma unroll
    for (int i = 0; i < 4; ++i) {
      const int dh = vdh0 + i * 16;
      gload16(vbase + (size_t)dh * 2048 + kt * 128 + ((vc0 ^ (dh & 15)) * 8),
              &Vs[(tid + i * 256) * 8]);
    }
    __syncthreads();  // drains vmcnt

#pragma unroll
    for (int mi = 0; mi < 2; ++mi) {
      // S^T[k][q]: s[ki], k = kt*128 + ki*16 + 4g + r, q = q0 + mi*16 + cc
      f32x4 s[8] = {};
      __builtin_amdgcn_s_setprio(1);
#pragma unroll
      for (int dc = 0; dc < 2; ++dc) {
        const bf16x8 qf = bq[mi][dc];
#pragma unroll
        for (int ki = 0; ki < 8; ++ki) {
          const int kr = ki * 16 + cc;
          const bf16x8 ak = *(const bf16x8*)&Ks[kr * 64 + (((4 * dc + g) ^ (kr & 7))) * 8];
          s[ki] = MFMA_16x16x32(ak, qf, s[ki]);
        }
      }
      __builtin_amdgcn_s_setprio(0);

      if (kt == qt) {  // causal mask on diagonal tile
        const int qq = w * 32 + mi * 16 + cc;
#pragma unroll
        for (int ki = 0; ki < 8; ++ki) {
          const int kb_ = ki * 16 + 4 * g;
#pragma unroll
          for (int r = 0; r < 4; ++r)
            if (kb_ + r > qq) s[ki][r] = -1e30f;
        }
      }

      // row max over 32 local + 4 lanes (g groups)
      float mx = fmaxf(fmaxf(s[0][0], s[0][1]), fmaxf(s[0][2], s[0][3]));
#pragma unroll
      for (int ki = 1; ki < 8; ++ki)
        mx = fmaxf(mx, fmaxf(fmaxf(s[ki][0], s[ki][1]), fmaxf(s[ki][2], s[ki][3])));
      mx = fmaxf(mx, __shfl_xor(mx, 16));
      mx = fmaxf(mx, __shfl_xor(mx, 32));
      const float mn = fmaxf(m_run[mi], mx * sc);
      const float sf = exp2f(m_run[mi] - mn);
      m_run[mi] = mn;
      l_run[mi] *= sf;

      // rescale acc rows (acc row q-offset = 4g+r; stats live at lane cc=q-offset)
      float sfr[4];
#pragma unroll
      for (int r = 0; r < 4; ++r) sfr[r] = __shfl(sf, (lane & 48) + 4 * g + r);
#pragma unroll
      for (int ni = 0; ni < 4; ++ni)
#pragma unroll
        for (int r = 0; r < 4; ++r) acc[mi][ni][r] *= sfr[r];

      // P = exp2(s*sc - mn), row-sum, convert to 16x16x16 A-fragments in-register
      bf16x4 pa[8];
      float rs = 0.f;
#pragma unroll
      for (int ki = 0; ki < 8; ++ki) {
        f32x4 p;
#pragma unroll
        for (int r = 0; r < 4; ++r) {
          p[r] = exp2f(s[ki][r] * sc - mn);
          rs += p[r];
        }
        pa[ki] = bf16x4{(__bf16)p[0], (__bf16)p[1], (__bf16)p[2], (__bf16)p[3]};
      }
      rs += __shfl_xor(rs, 16);
      rs += __shfl_xor(rs, 32);
      l_run[mi] += rs;

      // O += P V  (B: Vt[d=ni*16+cc][k=16ki+4g+j], 4 contiguous k = 8B)
      __builtin_amdgcn_s_setprio(1);
#pragma unroll
      for (int ki = 0; ki < 8; ++ki) {
        const int c = 2 * ki + (g >> 1);
#pragma unroll
        for (int ni = 0; ni < 4; ++ni) {
          const int dh = ni * 16 + cc;
          const bf16x4 bv =
              *(const bf16x4*)&Vs[dh * 128 + ((c ^ (dh & 15)) * 8) + (g & 1) * 4];
          acc[mi][ni] = MFMA16(pa[ki], bv, acc[mi][ni]);
        }
      }
      __builtin_amdgcn_s_setprio(0);
    }
  }

  // epilogue: O/l -> [b][t][h*64+dh] bf16
  const int b = bh >> 4, h = bh & 15;
#pragma unroll
  for (int mi = 0; mi < 2; ++mi) {
    float inv[4];
#pragma unroll
    for (int r = 0; r < 4; ++r)
      inv[r] = 1.f / __shfl(l_run[mi], (lane & 48) + 4 * g + r);
#pragma unroll
    for (int ni = 0; ni < 4; ++ni)
#pragma unroll
      for (int r = 0; r < 4; ++r) {
        const int tq = q0 + mi * 16 + 4 * g + r;
        Ob[((size_t)(b * 2048 + tq)) * 1024 + h * 64 + ni * 16 + cc] =
            f2bf(acc[mi][ni][r] * inv[r]);
      }
  }
}

// ---------- launch ----------

extern "C" void kernel_launch(void* const* d_in, const int* in_sizes, int n_in,
                              void* d_out, int out_size, void* d_ws, size_t ws_size,
                              hipStream_t stream) {
  const float* x     = (const float*)d_in[0];
  const float* w_qkv = (const float*)d_in[1];
  const float* b_qkv = (const float*)d_in[2];
  const float* w_out = (const float*)d_in[3];
  const float* b_out = (const float*)d_in[4];
  float* out = (float*)d_out;
  char* ws = (char*)d_ws;

  u16* xb    = (u16*)(ws + 0);          // 8192*1024 bf16 = 16 MB (then attn out)
  u16* wqkvT = (u16*)(ws + 16777216);   // 3072*1024 bf16 = 6 MB
  u16* woutT = (u16*)(ws + 23068672);   // 1024*1024 bf16 = 2 MB
  u16* qbuf  = (u16*)(ws + 25165824);   // 64*2048*64 bf16 = 16 MB
  u16* kbuf  = (u16*)(ws + 41943040);   // 16 MB
  u16* vbuf  = (u16*)(ws + 58720256);   // 16 MB (transposed: [bh][64][2048])

  cvt_to_bf16<<<4096, 256, 0, stream>>>(x, xb, 8388608);
  transpose_cvt<<<dim3(48, 16), 256, 0, stream>>>(w_qkv, wqkvT, 1024, 3072);
  transpose_cvt<<<dim3(16, 16), 256, 0, stream>>>(w_out, woutT, 1024, 1024);
  gemm_bt<0><<<24 * 64, 256, 0, stream>>>(xb, wqkvT, 1024, b_qkv,
                                          qbuf, kbuf, vbuf, nullptr, 3072, 24);
  flash_attn<<<1024, 256, 0, stream>>>(qbuf, kbuf, vbuf, xb);
  gemm_bt<1><<<8 * 64, 256, 0, stream>>>(xb, woutT, 1024, b_out,
                                         nullptr, nullptr, nullptr, out, 1024, 8);
}

// Round 3
// 196.264 us; speedup vs baseline: 1.1554x; 1.0564x over previous
//
#include <hip/hip_runtime.h>

typedef unsigned short u16;
typedef unsigned u32;
typedef float f32x4 __attribute__((ext_vector_type(4)));
typedef __bf16 bf16x8 __attribute__((ext_vector_type(8)));
typedef __bf16 bf16x2 __attribute__((ext_vector_type(2)));
typedef u32 u32x4 __attribute__((ext_vector_type(4)));
typedef u16 u16x4 __attribute__((ext_vector_type(4)));

#define MFMA_16x16x32(a, b, c) __builtin_amdgcn_mfma_f32_16x16x32_bf16((a), (b), (c), 0, 0, 0)

// ---------- helpers ----------

__device__ __forceinline__ u16 f2bf(float f) {
  unsigned u = __builtin_bit_cast(unsigned, f);
  unsigned r = ((u >> 16) & 1u) + 0x7FFFu;  // round-to-nearest-even
  return (u16)((u + r) >> 16);
}

__device__ __forceinline__ u32 pk2(float x, float y) {  // lo=x, hi=y as bf16
  bf16x2 v = {(__bf16)x, (__bf16)y};
  return __builtin_bit_cast(u32, v);
}

// async global->LDS, 16B per lane. LDS dest must be wave-uniform base + lane*16.
__device__ __forceinline__ void gload16(const void* g, void* l) {
  __builtin_amdgcn_global_load_lds(
      (const __attribute__((address_space(1))) void*)g,
      (__attribute__((address_space(3))) void*)l, 16, 0, 0);
}

// ---------- conversion kernels ----------

__global__ void cvt_to_bf16(const float* __restrict__ in, u16* __restrict__ out, int n) {
  const int i = (blockIdx.x * 256 + threadIdx.x) * 8;
  if (i >= n) return;
  const f32x4 a = *(const f32x4*)(in + i);
  const f32x4 b = *(const f32x4*)(in + i + 4);
  u16x4 u0, u1;
#pragma unroll
  for (int j = 0; j < 4; ++j) { u0[j] = f2bf(a[j]); u1[j] = f2bf(b[j]); }
  *(u16x4*)(out + i) = u0;
  *(u16x4*)(out + i + 4) = u1;
}

// in [rows][cols] fp32  ->  out [cols][rows] bf16   (64x64 LDS tiles)
__global__ void transpose_cvt(const float* __restrict__ in, u16* __restrict__ out,
                              int rows, int cols) {
  __shared__ float t[64][65];
  const int rb = blockIdx.y * 64, cb = blockIdx.x * 64;
  for (int i = threadIdx.x; i < 4096; i += 256) {
    const int r = i >> 6, c = i & 63;
    t[r][c] = in[(size_t)(rb + r) * cols + cb + c];
  }
  __syncthreads();
  for (int i = threadIdx.x; i < 4096; i += 256) {
    const int r = i >> 6, c = i & 63;
    out[(size_t)(cb + r) * rows + rb + c] = f2bf(t[c][r]);
  }
}

// ---------- GEMM: C[M][N] = A[M][K] * Bt[N][K]^T + bias ----------
// EPI=0: scatter to q[bh][t][64], k[bh][t][64], vT[bh][64][t-sigma] (bf16, +bias)
//        V's t index is sigma-permuted (swap bits 2,3 within each 32-group) so the
//        flash PV B-fragment is one contiguous b128 read.
// EPI=1: fp32 out[M][N] + bias
template <int EPI>
__global__ __launch_bounds__(256, 2) void gemm_bt(
    const u16* __restrict__ A, const u16* __restrict__ Bt, int K,
    const float* __restrict__ bias,
    u16* __restrict__ oq, u16* __restrict__ ok, u16* __restrict__ ov,
    float* __restrict__ of, int N, int nbx) {
  __shared__ __align__(16) u16 As[128 * 32];
  __shared__ __align__(16) u16 Bs[128 * 32];
  const int tid = threadIdx.x;
  const int lane = tid & 63, w = tid >> 6;
  const int g = lane >> 4, cc = lane & 15;
  const int wr = w >> 1, wc = w & 1;
  const int bid = blockIdx.x;
  const int bx = bid % nbx, by = bid / nbx;

  const u16* pa = A + (size_t)(by * 128 + (tid >> 2)) * K + (tid & 3) * 8;
  const u16* pb = Bt + (size_t)(bx * 128 + (tid >> 2)) * K + (tid & 3) * 8;
  u16* la = &As[tid * 8];
  u16* lb = &Bs[tid * 8];
  const size_t rowskip = (size_t)64 * K;

  f32x4 acc[4][4] = {};
  const int aoff = (wr * 64 + cc) * 32 + g * 8;
  const int boff = (wc * 64 + cc) * 32 + g * 8;

  for (int k0 = 0; k0 < K; k0 += 32) {
    gload16(pa + k0, la);
    gload16(pa + rowskip + k0, la + 2048);
    gload16(pb + k0, lb);
    gload16(pb + rowskip + k0, lb + 2048);
    __syncthreads();
    bf16x8 af[4], bf[4];
#pragma unroll
    for (int mi = 0; mi < 4; ++mi) af[mi] = *(const bf16x8*)&As[aoff + mi * 512];
#pragma unroll
    for (int ni = 0; ni < 4; ++ni) bf[ni] = *(const bf16x8*)&Bs[boff + ni * 512];
#pragma unroll
    for (int mi = 0; mi < 4; ++mi)
#pragma unroll
      for (int ni = 0; ni < 4; ++ni)
        acc[mi][ni] = MFMA_16x16x32(af[mi], bf[ni], acc[mi][ni]);
    __syncthreads();
  }

  const int m00 = by * 128 + wr * 64 + 4 * g;
  const int n00 = bx * 128 + wc * 64;
#pragma unroll
  for (int ni = 0; ni < 4; ++ni) {
    const int n = n00 + ni * 16 + cc;
    const float bn = bias[n];
    if constexpr (EPI == 0) {
      const int which = n >> 10;          // 0=q 1=k 2=v (wave-uniform)
      const int d = n & 1023;
      const int h = d >> 6, dh = d & 63;
#pragma unroll
      for (int mi = 0; mi < 4; ++mi) {
        const int mb = m00 + mi * 16;
        const int b = mb >> 11, t = mb & 2047;
        if (which == 2) {
          u16x4 pk;
#pragma unroll
          for (int r = 0; r < 4; ++r) pk[r] = f2bf(acc[mi][ni][r] + bn);
          const int tt = (t & ~12) | ((t & 4) << 1) | ((t & 8) >> 1);  // sigma
          *(u16x4*)&ov[((size_t)((b * 16 + h) * 64 + dh)) * 2048 + tt] = pk;
        } else {
          u16* dst = (which == 0 ? oq : ok) + ((size_t)((b * 16 + h) * 2048 + t)) * 64 + dh;
#pragma unroll
          for (int r = 0; r < 4; ++r) dst[(size_t)r * 64] = f2bf(acc[mi][ni][r] + bn);
        }
      }
    } else {
#pragma unroll
      for (int mi = 0; mi < 4; ++mi) {
        const int m = m00 + mi * 16;
#pragma unroll
        for (int r = 0; r < 4; ++r) of[(size_t)(m + r) * N + n] = acc[mi][ni][r] + bn;
      }
    }
  }
}

// ---------- causal flash attention ----------
// Swapped QK^T (S^T = mfma(K,Q)) keeps softmax stats 2 scalars/lane.
// PV: per 32-k block, P packed to bf16 pairs, redistributed across the l<->l+32
// boundary (shfl_xor 32 + select) into a k-permuted (sigma = swap bit2/bit3)
// mfma_16x16x32 A-fragment; V stored sigma-permuted so B is one b128 read,
// 16B-chunk XOR-swizzled -> conflict-free.
__global__ __launch_bounds__(256, 4) void flash_attn(
    const u16* __restrict__ Qb, const u16* __restrict__ Kb,
    const u16* __restrict__ Vt, u16* __restrict__ Ob) {
  __shared__ __align__(16) u16 Ks[128 * 64];
  __shared__ __align__(16) u16 Vs[64 * 128];

  const int bid = blockIdx.x;
  // per-CU load balance: blocks c,c+256,c+512,c+768 share a CU; each CU's four
  // qt values sum to 30 (34 tile-iters) for every c.
  const int tq4 = bid >> 6, t0 = tq4 & 3, ti = tq4 >> 2;
  const int qt = (ti == 0) ? 15 - t0 : (ti == 1) ? 8 + t0 : (ti == 2) ? 7 - t0 : t0;
  const int bh = bid & 63;
  const int tid = threadIdx.x;
  const int lane = tid & 63, w = tid >> 6;
  const int g = lane >> 4, cc = lane & 15;
  const int q0 = qt * 128 + w * 32;

  // Q as B-operand fragments: Q[q0+mi*16+cc][dc*32+g*8 .. +7]
  bf16x8 bq[2][2];
  {
    const u16* qp = Qb + ((size_t)bh * 2048 + q0 + cc) * 64 + g * 8;
#pragma unroll
    for (int mi = 0; mi < 2; ++mi)
#pragma unroll
      for (int dc = 0; dc < 2; ++dc)
        bq[mi][dc] = *(const bf16x8*)(qp + (size_t)mi * 16 * 64 + dc * 32);
  }

  f32x4 acc[2][4] = {};
  float m_run[2] = {-1e30f, -1e30f};
  float l_run[2] = {0.f, 0.f};
  const float sc = 0.18033688011112042f;  // (1/8) * log2(e)

  const int kr0 = tid >> 3, kc0 = tid & 7;
  const int vdh0 = tid >> 4, vc0 = tid & 15;
  const u16* kbase = Kb + (size_t)bh * 2048 * 64;
  const u16* vbase = Vt + (size_t)bh * 64 * 2048;
  const bool lo2 = (g < 2);

  for (int kt = 0; kt <= qt; ++kt) {
    __syncthreads();  // previous tile's LDS reads done
#pragma unroll
    for (int i = 0; i < 4; ++i) {
      const int kr = kr0 + i * 32;
      gload16(kbase + ((size_t)(kt * 128 + kr)) * 64 + ((kc0 ^ (kr & 7)) * 8),
              &Ks[(tid + i * 256) * 8]);
    }
#pragma unroll
    for (int i = 0; i < 4; ++i) {
      const int dh = vdh0 + i * 16;
      gload16(vbase + (size_t)dh * 2048 + kt * 128 + ((vc0 ^ (dh & 15)) * 8),
              &Vs[(tid + i * 256) * 8]);
    }
    __syncthreads();  // drains vmcnt

#pragma unroll
    for (int mi = 0; mi < 2; ++mi) {
      // S^T[k][q]: s[ki], k = kt*128 + ki*16 + 4g + r, q = q0 + mi*16 + cc
      f32x4 s[8] = {};
      __builtin_amdgcn_s_setprio(1);
#pragma unroll
      for (int dc = 0; dc < 2; ++dc) {
        const bf16x8 qf = bq[mi][dc];
#pragma unroll
        for (int ki = 0; ki < 8; ++ki) {
          const int kr = ki * 16 + cc;
          const bf16x8 ak = *(const bf16x8*)&Ks[kr * 64 + (((4 * dc + g) ^ (kr & 7))) * 8];
          s[ki] = MFMA_16x16x32(ak, qf, s[ki]);
        }
      }
      __builtin_amdgcn_s_setprio(0);

      if (kt == qt) {  // causal mask on diagonal tile
        const int qq = w * 32 + mi * 16 + cc;
#pragma unroll
        for (int ki = 0; ki < 8; ++ki) {
          const int kb_ = ki * 16 + 4 * g;
#pragma unroll
          for (int r = 0; r < 4; ++r)
            if (kb_ + r > qq) s[ki][r] = -1e30f;
        }
      }

      // row max (32 local + lanes cc, cc+16, cc+32, cc+48)
      float mx = fmaxf(fmaxf(s[0][0], s[0][1]), fmaxf(s[0][2], s[0][3]));
#pragma unroll
      for (int ki = 1; ki < 8; ++ki)
        mx = fmaxf(mx, fmaxf(fmaxf(s[ki][0], s[ki][1]), fmaxf(s[ki][2], s[ki][3])));
      mx = fmaxf(mx, __shfl_xor(mx, 16));
      mx = fmaxf(mx, __shfl_xor(mx, 32));
      const float pm = mx * sc;

      // defer-max (T13): only rescale when max grew by > 8 (P bounded by 2^8)
      if (!__all(pm - m_run[mi] <= 8.f)) {
        const float mn = fmaxf(m_run[mi], pm);
        const float sf = exp2f(m_run[mi] - mn);
        m_run[mi] = mn;
        l_run[mi] *= sf;
        float sfr[4];
#pragma unroll
        for (int r = 0; r < 4; ++r) sfr[r] = __shfl(sf, (lane & 48) + 4 * g + r);
#pragma unroll
        for (int ni = 0; ni < 4; ++ni)
#pragma unroll
          for (int r = 0; r < 4; ++r) acc[mi][ni][r] *= sfr[r];
      }
      const float mcur = m_run[mi];

      float rs = 0.f;
#pragma unroll
      for (int ko = 0; ko < 4; ++ko) {
        // P for k-block 32ko: even ki (k=+4g+r) and odd ki (k=+16+4g+r)
        f32x4 pe, po;
#pragma unroll
        for (int r = 0; r < 4; ++r) {
          pe[r] = exp2f(s[2 * ko][r] * sc - mcur);
          po[r] = exp2f(s[2 * ko + 1][r] * sc - mcur);
          rs += pe[r] + po[r];
        }
        const u32 aw = pk2(pe[0], pe[1]), bw = pk2(pe[2], pe[3]);
        const u32 cw = pk2(po[0], po[1]), dw = pk2(po[2], po[3]);
        // exchange across wave halves: lane needs partner(l^32)'s {a,b} (if hi)
        // or partner's {c,d} (if lo) to assemble sigma-ordered A-fragment
        const u32 r_ac = __shfl_xor(lo2 ? cw : aw, 32);
        const u32 r_bd = __shfl_xor(lo2 ? dw : bw, 32);
        const u32 W0 = lo2 ? aw : r_ac;
        const u32 W1 = lo2 ? bw : r_bd;
        const u32 W2 = lo2 ? r_ac : cw;
        const u32 W3 = lo2 ? r_bd : dw;
        const u32x4 wv = {W0, W1, W2, W3};
        const bf16x8 pf = __builtin_bit_cast(bf16x8, wv);
        __builtin_amdgcn_s_setprio(1);
#pragma unroll
        for (int ni = 0; ni < 4; ++ni) {
          const bf16x8 bv =
              *(const bf16x8*)&Vs[(ni * 16 + cc) * 128 + (((4 * ko + g) ^ cc) * 8)];
          acc[mi][ni] = MFMA_16x16x32(pf, bv, acc[mi][ni]);
        }
        __builtin_amdgcn_s_setprio(0);
      }
      rs += __shfl_xor(rs, 16);
      rs += __shfl_xor(rs, 32);
      l_run[mi] += rs;
    }
  }

  // epilogue: O/l -> [b][t][h*64+dh] bf16
  const int b = bh >> 4, h = bh & 15;
#pragma unroll
  for (int mi = 0; mi < 2; ++mi) {
    float inv[4];
#pragma unroll
    for (int r = 0; r < 4; ++r)
      inv[r] = 1.f / __shfl(l_run[mi], (lane & 48) + 4 * g + r);
#pragma unroll
    for (int ni = 0; ni < 4; ++ni)
#pragma unroll
      for (int r = 0; r < 4; ++r) {
        const int tq = q0 + mi * 16 + 4 * g + r;
        Ob[((size_t)(b * 2048 + tq)) * 1024 + h * 64 + ni * 16 + cc] =
            f2bf(acc[mi][ni][r] * inv[r]);
      }
  }
}

// ---------- launch ----------

extern "C" void kernel_launch(void* const* d_in, const int* in_sizes, int n_in,
                              void* d_out, int out_size, void* d_ws, size_t ws_size,
                              hipStream_t stream) {
  const float* x     = (const float*)d_in[0];
  const float* w_qkv = (const float*)d_in[1];
  const float* b_qkv = (const float*)d_in[2];
  const float* w_out = (const float*)d_in[3];
  const float* b_out = (const float*)d_in[4];
  float* out = (float*)d_out;
  char* ws = (char*)d_ws;

  u16* xb    = (u16*)(ws + 0);          // 8192*1024 bf16 = 16 MB (then attn out)
  u16* wqkvT = (u16*)(ws + 16777216);   // 3072*1024 bf16 = 6 MB
  u16* woutT = (u16*)(ws + 23068672);   // 1024*1024 bf16 = 2 MB
  u16* qbuf  = (u16*)(ws + 25165824);   // 64*2048*64 bf16 = 16 MB
  u16* kbuf  = (u16*)(ws + 41943040);   // 16 MB
  u16* vbuf  = (u16*)(ws + 58720256);   // 16 MB ([bh][64][2048], t sigma-permuted)

  cvt_to_bf16<<<4096, 256, 0, stream>>>(x, xb, 8388608);
  transpose_cvt<<<dim3(48, 16), 256, 0, stream>>>(w_qkv, wqkvT, 1024, 3072);
  transpose_cvt<<<dim3(16, 16), 256, 0, stream>>>(w_out, woutT, 1024, 1024);
  gemm_bt<0><<<24 * 64, 256, 0, stream>>>(xb, wqkvT, 1024, b_qkv,
                                          qbuf, kbuf, vbuf, nullptr, 3072, 24);
  flash_attn<<<1024, 256, 0, stream>>>(qbuf, kbuf, vbuf, xb);
  gemm_bt<1><<<8 * 64, 256, 0, stream>>>(xb, woutT, 1024, b_out,
                                         nullptr, nullptr, nullptr, out, 1024, 8);
}

// Round 4
// 190.953 us; speedup vs baseline: 1.1875x; 1.0278x over previous
//
#include <hip/hip_runtime.h>

typedef unsigned short u16;
typedef unsigned u32;
typedef float f32x4 __attribute__((ext_vector_type(4)));
typedef __bf16 bf16x8 __attribute__((ext_vector_type(8)));
typedef __bf16 bf16x2 __attribute__((ext_vector_type(2)));
typedef u32 u32x4 __attribute__((ext_vector_type(4)));
typedef u16 u16x4 __attribute__((ext_vector_type(4)));
typedef int i32x2 __attribute__((ext_vector_type(2)));

#define MFMA_16x16x32(a, b, c) __builtin_amdgcn_mfma_f32_16x16x32_bf16((a), (b), (c), 0, 0, 0)

#if __has_builtin(__builtin_amdgcn_exp2f)
#define EXP2(x) __builtin_amdgcn_exp2f(x)
#else
#define EXP2(x) exp2f(x)
#endif

// ---------- helpers ----------

__device__ __forceinline__ u16 f2bf(float f) {
  unsigned u = __builtin_bit_cast(unsigned, f);
  unsigned r = ((u >> 16) & 1u) + 0x7FFFu;  // round-to-nearest-even
  return (u16)((u + r) >> 16);
}

__device__ __forceinline__ u32 pk2(float x, float y) {  // lo=x, hi=y as bf16
  bf16x2 v = {(__bf16)x, (__bf16)y};
  return __builtin_bit_cast(u32, v);
}

// async global->LDS, 16B per lane. LDS dest must be wave-uniform base + lane*16.
__device__ __forceinline__ void gload16(const void* g, void* l) {
  __builtin_amdgcn_global_load_lds(
      (const __attribute__((address_space(1))) void*)g,
      (__attribute__((address_space(3))) void*)l, 16, 0, 0);
}

// ---------- conversion kernels ----------

__global__ void cvt_to_bf16(const float* __restrict__ in, u16* __restrict__ out, int n) {
  const int i = (blockIdx.x * 256 + threadIdx.x) * 8;
  if (i >= n) return;
  const f32x4 a = *(const f32x4*)(in + i);
  const f32x4 b = *(const f32x4*)(in + i + 4);
  u16x4 u0, u1;
#pragma unroll
  for (int j = 0; j < 4; ++j) { u0[j] = f2bf(a[j]); u1[j] = f2bf(b[j]); }
  *(u16x4*)(out + i) = u0;
  *(u16x4*)(out + i + 4) = u1;
}

// in [rows][cols] fp32  ->  out [cols][rows] bf16   (64x64 LDS tiles)
__global__ void transpose_cvt(const float* __restrict__ in, u16* __restrict__ out,
                              int rows, int cols) {
  __shared__ float t[64][65];
  const int rb = blockIdx.y * 64, cb = blockIdx.x * 64;
  for (int i = threadIdx.x; i < 4096; i += 256) {
    const int r = i >> 6, c = i & 63;
    t[r][c] = in[(size_t)(rb + r) * cols + cb + c];
  }
  __syncthreads();
  for (int i = threadIdx.x; i < 4096; i += 256) {
    const int r = i >> 6, c = i & 63;
    out[(size_t)(cb + r) * rows + rb + c] = f2bf(t[c][r]);
  }
}

// ---------- GEMM: C[M][N] = A[M][K] * Bt[N][K]^T + bias ----------
// EPI=0: scatter to q[bh][t][64], k[bh][t][64], vT[bh][64][t-sigma] (bf16, +bias)
//        V's t index is sigma-permuted (swap bits 2,3 within each 32-group) so the
//        flash PV A-fragment assembly (permlane32_swap pairs) lines up with V.
// EPI=1: fp32 out[M][N] + bias
template <int EPI>
__global__ __launch_bounds__(256, 2) void gemm_bt(
    const u16* __restrict__ A, const u16* __restrict__ Bt, int K,
    const float* __restrict__ bias,
    u16* __restrict__ oq, u16* __restrict__ ok, u16* __restrict__ ov,
    float* __restrict__ of, int N, int nbx) {
  __shared__ __align__(16) u16 As[128 * 32];
  __shared__ __align__(16) u16 Bs[128 * 32];
  const int tid = threadIdx.x;
  const int lane = tid & 63, w = tid >> 6;
  const int g = lane >> 4, cc = lane & 15;
  const int wr = w >> 1, wc = w & 1;
  const int bid = blockIdx.x;
  const int bx = bid % nbx, by = bid / nbx;

  const u16* pa = A + (size_t)(by * 128 + (tid >> 2)) * K + (tid & 3) * 8;
  const u16* pb = Bt + (size_t)(bx * 128 + (tid >> 2)) * K + (tid & 3) * 8;
  u16* la = &As[tid * 8];
  u16* lb = &Bs[tid * 8];
  const size_t rowskip = (size_t)64 * K;

  f32x4 acc[4][4] = {};
  const int aoff = (wr * 64 + cc) * 32 + g * 8;
  const int boff = (wc * 64 + cc) * 32 + g * 8;

  for (int k0 = 0; k0 < K; k0 += 32) {
    gload16(pa + k0, la);
    gload16(pa + rowskip + k0, la + 2048);
    gload16(pb + k0, lb);
    gload16(pb + rowskip + k0, lb + 2048);
    __syncthreads();
    bf16x8 af[4], bf[4];
#pragma unroll
    for (int mi = 0; mi < 4; ++mi) af[mi] = *(const bf16x8*)&As[aoff + mi * 512];
#pragma unroll
    for (int ni = 0; ni < 4; ++ni) bf[ni] = *(const bf16x8*)&Bs[boff + ni * 512];
#pragma unroll
    for (int mi = 0; mi < 4; ++mi)
#pragma unroll
      for (int ni = 0; ni < 4; ++ni)
        acc[mi][ni] = MFMA_16x16x32(af[mi], bf[ni], acc[mi][ni]);
    __syncthreads();
  }

  const int m00 = by * 128 + wr * 64 + 4 * g;
  const int n00 = bx * 128 + wc * 64;
#pragma unroll
  for (int ni = 0; ni < 4; ++ni) {
    const int n = n00 + ni * 16 + cc;
    const float bn = bias[n];
    if constexpr (EPI == 0) {
      const int which = n >> 10;          // 0=q 1=k 2=v (wave-uniform)
      const int d = n & 1023;
      const int h = d >> 6, dh = d & 63;
#pragma unroll
      for (int mi = 0; mi < 4; ++mi) {
        const int mb = m00 + mi * 16;
        const int b = mb >> 11, t = mb & 2047;
        if (which == 2) {
          u16x4 pk;
#pragma unroll
          for (int r = 0; r < 4; ++r) pk[r] = f2bf(acc[mi][ni][r] + bn);
          const int tt = (t & ~12) | ((t & 4) << 1) | ((t & 8) >> 1);  // sigma
          *(u16x4*)&ov[((size_t)((b * 16 + h) * 64 + dh)) * 2048 + tt] = pk;
        } else {
          u16* dst = (which == 0 ? oq : ok) + ((size_t)((b * 16 + h) * 2048 + t)) * 64 + dh;
#pragma unroll
          for (int r = 0; r < 4; ++r) dst[(size_t)r * 64] = f2bf(acc[mi][ni][r] + bn);
        }
      }
    } else {
#pragma unroll
      for (int mi = 0; mi < 4; ++mi) {
        const int m = m00 + mi * 16;
#pragma unroll
        for (int r = 0; r < 4; ++r) of[(size_t)(m + r) * N + n] = acc[mi][ni][r] + bn;
      }
    }
  }
}

// ---------- causal flash attention ----------
// Swapped QK^T (S^T = mfma(K,Q)); softmax stats 2 scalars/lane; PV A-fragment
// built in-register via 2x permlane32_swap per 32-k block (sigma baked into V).
// LDS is laid out in FRAGMENT order [frag][lane][8]: every ds_read_b128 is
// (lane*16 + compile-time imm) -> zero per-tile address VALU, conflict-free.
__global__ __launch_bounds__(256, 4) void flash_attn(
    const u16* __restrict__ Qb, const u16* __restrict__ Kb,
    const u16* __restrict__ Vt, u16* __restrict__ Ob) {
  __shared__ __align__(16) u16 Ks[8192];  // 16 frags x 64 lanes x 8
  __shared__ __align__(16) u16 Vs[8192];

  const int bid = blockIdx.x;
  // per-CU load balance: blocks c,c+256,c+512,c+768 share a CU; qt quadruples sum to 30.
  const int tq4 = bid >> 6, t0 = tq4 & 3, ti = tq4 >> 2;
  const int qt = (ti == 0) ? 15 - t0 : (ti == 1) ? 8 + t0 : (ti == 2) ? 7 - t0 : t0;
  const int bh = bid & 63;
  const int tid = threadIdx.x;
  const int lane = tid & 63, w = tid >> 6;
  const int g = lane >> 4, cc = lane & 15;
  const int q0 = qt * 128 + w * 32;

  // Q as B-operand fragments: Q[q0+mi*16+cc][dc*32+g*8 .. +7]
  bf16x8 bq[2][2];
  {
    const u16* qp = Qb + ((size_t)bh * 2048 + q0 + cc) * 64 + g * 8;
#pragma unroll
    for (int mi = 0; mi < 2; ++mi)
#pragma unroll
      for (int dc = 0; dc < 2; ++dc)
        bq[mi][dc] = *(const bf16x8*)(qp + (size_t)mi * 16 * 64 + dc * 32);
  }

  // staging pointers: K frag f=i*4+w holds K[ki*16+cc][32dc+8g+e], ki=f&7, dc=f>>3;
  // V frag f=i*4+w = (ko=i, ni=w) holds Vg[ni*16+cc][(4ko+g)*8+e] (t sigma-permuted).
  const char* kp[4];
  const char* vp[4];
  u16* kl[4];
  u16* vl[4];
  {
    const char* kbase = (const char*)(Kb + (size_t)bh * 2048 * 64);
    const char* vbase = (const char*)(Vt + (size_t)bh * 64 * 2048);
#pragma unroll
    for (int i = 0; i < 4; ++i) {
      const int f = i * 4 + w, ki = f & 7, dc = f >> 3;
      kp[i] = kbase + ((ki * 16 + cc) * 64 + dc * 32 + g * 8) * 2;
      vp[i] = vbase + ((w * 16 + cc) * 2048 + (4 * i + g) * 8) * 2;
      kl[i] = &Ks[f * 512 + lane * 8];
      vl[i] = &Vs[f * 512 + lane * 8];
    }
  }
  const u16* krd = &Ks[lane * 8];
  const u16* vrd = &Vs[lane * 8];

  f32x4 acc[2][4] = {};
  float m_run[2] = {-1e30f, -1e30f};
  float l_run[2] = {0.f, 0.f};
  const float sc = 0.18033688011112042f;  // (1/8) * log2(e)

  for (int kt = 0; kt <= qt; ++kt) {
    __syncthreads();  // previous tile's LDS reads done
#pragma unroll
    for (int i = 0; i < 4; ++i) gload16(kp[i], kl[i]);
#pragma unroll
    for (int i = 0; i < 4; ++i) gload16(vp[i], vl[i]);
#pragma unroll
    for (int i = 0; i < 4; ++i) { kp[i] += 128 * 64 * 2; vp[i] += 128 * 2; }
    __syncthreads();  // drains vmcnt

#pragma unroll
    for (int mi = 0; mi < 2; ++mi) {
      // S^T[k][q]: s[ki], k = kt*128 + ki*16 + 4g + r, q = q0 + mi*16 + cc
      f32x4 s[8] = {};
      __builtin_amdgcn_s_setprio(1);
#pragma unroll
      for (int dc = 0; dc < 2; ++dc) {
        const bf16x8 qf = bq[mi][dc];
#pragma unroll
        for (int ki = 0; ki < 8; ++ki) {
          const bf16x8 ak = *(const bf16x8*)(krd + (dc * 8 + ki) * 512);
          s[ki] = MFMA_16x16x32(ak, qf, s[ki]);
        }
      }
      __builtin_amdgcn_s_setprio(0);

      if (kt == qt) {  // causal mask on diagonal tile
        const int qq = w * 32 + mi * 16 + cc;
#pragma unroll
        for (int ki = 0; ki < 8; ++ki) {
          const int kb_ = ki * 16 + 4 * g;
#pragma unroll
          for (int r = 0; r < 4; ++r)
            if (kb_ + r > qq) s[ki][r] = -1e30f;
        }
      }

      // row max (32 local + lanes cc, cc+16, cc+32, cc+48)
      float mx = fmaxf(fmaxf(s[0][0], s[0][1]), fmaxf(s[0][2], s[0][3]));
#pragma unroll
      for (int ki = 1; ki < 8; ++ki)
        mx = fmaxf(mx, fmaxf(fmaxf(s[ki][0], s[ki][1]), fmaxf(s[ki][2], s[ki][3])));
      mx = fmaxf(mx, __shfl_xor(mx, 16));
      mx = fmaxf(mx, __shfl_xor(mx, 32));
      const float pm = mx * sc;

      // defer-max (T13): only rescale when max grew by > 8 (P bounded by 2^8)
      if (!__all(pm - m_run[mi] <= 8.f)) {
        const float mn = fmaxf(m_run[mi], pm);
        const float sf = EXP2(m_run[mi] - mn);
        m_run[mi] = mn;
        l_run[mi] *= sf;
        float sfr[4];
#pragma unroll
        for (int r = 0; r < 4; ++r) sfr[r] = __shfl(sf, (lane & 48) + 4 * g + r);
#pragma unroll
        for (int ni = 0; ni < 4; ++ni)
#pragma unroll
          for (int r = 0; r < 4; ++r) acc[mi][ni][r] *= sfr[r];
      }
      const float mcur = m_run[mi];

      f32x4 rsv = {};
#pragma unroll
      for (int ko = 0; ko < 4; ++ko) {
        // P for k-block 32ko: even ki (k=+4g+r) and odd ki (k=+16+4g+r)
        f32x4 pe, po;
#pragma unroll
        for (int r = 0; r < 4; ++r) {
          pe[r] = EXP2(__builtin_fmaf(s[2 * ko][r], sc, -mcur));
          po[r] = EXP2(__builtin_fmaf(s[2 * ko + 1][r], sc, -mcur));
        }
        rsv += pe;
        rsv += po;
        const u32 aw = pk2(pe[0], pe[1]), bw2 = pk2(pe[2], pe[3]);
        const u32 cw = pk2(po[0], po[1]), dw = pk2(po[2], po[3]);
#if __has_builtin(__builtin_amdgcn_permlane32_swap)
        const i32x2 s1 = __builtin_amdgcn_permlane32_swap((int)aw, (int)cw, false, false);
        const i32x2 s2 = __builtin_amdgcn_permlane32_swap((int)bw2, (int)dw, false, false);
        const u32x4 wv = {(u32)s1[0], (u32)s2[0], (u32)s1[1], (u32)s2[1]};
#else
        const bool lo2 = (g < 2);
        const u32 r_ac = __shfl_xor(lo2 ? cw : aw, 32);
        const u32 r_bd = __shfl_xor(lo2 ? dw : bw2, 32);
        const u32x4 wv = {lo2 ? aw : r_ac, lo2 ? bw2 : r_bd,
                          lo2 ? r_ac : cw, lo2 ? r_bd : dw};
#endif
        const bf16x8 pf = __builtin_bit_cast(bf16x8, wv);
        __builtin_amdgcn_s_setprio(1);
#pragma unroll
        for (int ni = 0; ni < 4; ++ni) {
          const bf16x8 bv = *(const bf16x8*)(vrd + (ko * 4 + ni) * 512);
          acc[mi][ni] = MFMA_16x16x32(pf, bv, acc[mi][ni]);
        }
        __builtin_amdgcn_s_setprio(0);
      }
      float rs = (rsv[0] + rsv[1]) + (rsv[2] + rsv[3]);
      rs += __shfl_xor(rs, 16);
      rs += __shfl_xor(rs, 32);
      l_run[mi] += rs;
    }
  }

  // epilogue: O/l -> [b][t][h*64+dh] bf16
  const int b = bh >> 4, h = bh & 15;
#pragma unroll
  for (int mi = 0; mi < 2; ++mi) {
    float inv[4];
#pragma unroll
    for (int r = 0; r < 4; ++r)
      inv[r] = 1.f / __shfl(l_run[mi], (lane & 48) + 4 * g + r);
#pragma unroll
    for (int ni = 0; ni < 4; ++ni)
#pragma unroll
      for (int r = 0; r < 4; ++r) {
        const int tq = q0 + mi * 16 + 4 * g + r;
        Ob[((size_t)(b * 2048 + tq)) * 1024 + h * 64 + ni * 16 + cc] =
            f2bf(acc[mi][ni][r] * inv[r]);
      }
  }
}

// ---------- launch ----------

extern "C" void kernel_launch(void* const* d_in, const int* in_sizes, int n_in,
                              void* d_out, int out_size, void* d_ws, size_t ws_size,
                              hipStream_t stream) {
  const float* x     = (const float*)d_in[0];
  const float* w_qkv = (const float*)d_in[1];
  const float* b_qkv = (const float*)d_in[2];
  const float* w_out = (const float*)d_in[3];
  const float* b_out = (const float*)d_in[4];
  float* out = (float*)d_out;
  char* ws = (char*)d_ws;

  u16* xb    = (u16*)(ws + 0);          // 8192*1024 bf16 = 16 MB (then attn out)
  u16* wqkvT = (u16*)(ws + 16777216);   // 3072*1024 bf16 = 6 MB
  u16* woutT = (u16*)(ws + 23068672);   // 1024*1024 bf16 = 2 MB
  u16* qbuf  = (u16*)(ws + 25165824);   // 64*2048*64 bf16 = 16 MB
  u16* kbuf  = (u16*)(ws + 41943040);   // 16 MB
  u16* vbuf  = (u16*)(ws + 58720256);   // 16 MB ([bh][64][2048], t sigma-permuted)

  cvt_to_bf16<<<4096, 256, 0, stream>>>(x, xb, 8388608);
  transpose_cvt<<<dim3(48, 16), 256, 0, stream>>>(w_qkv, wqkvT, 1024, 3072);
  transpose_cvt<<<dim3(16, 16), 256, 0, stream>>>(w_out, woutT, 1024, 1024);
  gemm_bt<0><<<24 * 64, 256, 0, stream>>>(xb, wqkvT, 1024, b_qkv,
                                          qbuf, kbuf, vbuf, nullptr, 3072, 24);
  flash_attn<<<1024, 256, 0, stream>>>(qbuf, kbuf, vbuf, xb);
  gemm_bt<1><<<8 * 64, 256, 0, stream>>>(xb, woutT, 1024, b_out,
                                         nullptr, nullptr, nullptr, out, 1024, 8);
}